// Round 9
// baseline (21.856 us; speedup 1.0000x reference)
//
#include <hip/hip_runtime.h>
#include <hip/hip_bf16.h>

#define CIN_ 16
#define COUT_ 32
#define NBATCH_ 16
#define H_ 64
#define W_ 64
#define F_ 10                   // silu + 8 bases + zero pad -> K=160 per tap
#define LPIX_ 336               // LDS bytes per pixel (320 data + 16 pad)
#define PXT_ 18                 // staged pixels per row (16 out + 2 halo)
#define LROWT_ (PXT_ * LPIX_)   // 6048 B per staged input row
#define ROWS_ 6                 // staged input rows (4 output rows + 2 halo)
#define NSITE_ (ROWS_ * PXT_)   // 108 (row,px) sites per ci
#define NIT_ 7                  // ceil(108/16) prefetch iterations

typedef __attribute__((ext_vector_type(8))) short short8;
typedef __attribute__((ext_vector_type(4))) float f32x4;

__device__ __forceinline__ unsigned short f2bf(float f) {
    unsigned u = __builtin_bit_cast(unsigned, f);
    u += 0x7FFFu + ((u >> 16) & 1u);
    return (unsigned short)(u >> 16);
}
__device__ __forceinline__ unsigned pack2(float lo, float hi) {
    return (unsigned)f2bf(lo) | ((unsigned)f2bf(hi) << 16);
}

// Pack weights into per-lane MFMA B-fragment order (16x16x32):
// layout [tap(9)][nt(2)][c(5)][lane(64)][8 bf16]; k = ci*10 + f;
// per-lane k = c*32 + (lane>>4)*8 + j, n = nt*16 + (lane&15).
// Thread owns (n,ci,tap): contiguous sw loads, 10 scattered u16 stores.
// Every wpk byte written exactly once (poison-safe).
__global__ void kan_packw(const float* __restrict__ bw, const float* __restrict__ sw,
                          const float* __restrict__ sc, unsigned short* __restrict__ wpk) {
    int e = blockIdx.x * 256 + threadIdx.x;   // e = (n*CIN_+ci)*9+tap
    if (e >= 32 * 16 * 9) return;
    int n = e / 144;
    int ci = (e / 9) & 15;
    int tap = e % 9;
    float bwv = bw[e];
    float scv = sc[e];
    float4 s0 = *(const float4*)(sw + (size_t)e * 8);
    float4 s1 = *(const float4*)(sw + (size_t)e * 8 + 4);
    float swv[8] = {s0.x, s0.y, s0.z, s0.w, s1.x, s1.y, s1.z, s1.w};
    int nt = n >> 4, nl = n & 15;
#pragma unroll
    for (int f = 0; f < 10; ++f) {
        float v = (f == 0) ? bwv : (f <= 8 ? swv[f - 1] * scv : 0.0f);
        int k = ci * 10 + f;
        int c = k >> 5, r = k & 31;
        int lane = ((r >> 3) << 4) | nl;
        int j = r & 7;
        wpk[((size_t)(((tap * 2 + nt) * 5 + c)) * 64 + lane) * 8 + j] = f2bf(v);
    }
}

// Fused featurize + implicit-GEMM conv, 16x16x32 MFMA, tap-split waves.
// Block = (batch, 4 output rows, 16-px quarter). 36.3 KB LDS -> 4 blocks/CU
// = 4 waves/SIMD. Wave wv -> (row-pair p = wv&1, tap-half th = wv>>1):
// M2xN2 tile (2 rows x 16 px x 32 ch) over taps {th, th+2, ...}. Each A-read
// feeds 2 MFMAs (LDS traffic halved vs R8); per-wave B bytes unchanged.
// Partner waves (same p, other th) reduce partials via LDS scratch.
__global__ __launch_bounds__(256, 4) void kan_fused(const float* __restrict__ x,
                                                    const unsigned short* __restrict__ wpk,
                                                    float* __restrict__ out) {
    __shared__ __align__(16) char lA[ROWS_ * LROWT_];   // 36,288 B (>= 8.5 KB scratch)
    int tid = threadIdx.x;
    int bb = blockIdx.x >> 6;
    int rem = blockIdx.x & 63;
    int h0 = (rem >> 2) * 4;
    int w0 = (rem & 3) * 16;

    // ---- Phase 1: features into LDS; x-loads register-prefetched ----
    {
        int ci = tid >> 4;
        int l = tid & 15;
        const float* xb = x + ((size_t)bb * CIN_ + ci) * (H_ * W_);
        float xr[NIT_];
#pragma unroll
        for (int it = 0; it < NIT_; ++it) {
            int s = it * 16 + l;
            int r = s / PXT_;
            int lpx = s - r * PXT_;
            int hy = h0 + r - 1;
            int wx = w0 + lpx - 1;
            bool v = (s < NSITE_) && (hy >= 0) && (hy < H_) && (wx >= 0) && (wx < W_);
            xr[it] = v ? xb[hy * W_ + wx] : 0.f;   // all loads in flight together
        }
#pragma unroll
        for (int it = 0; it < NIT_; ++it) {
            int s = it * 16 + l;
            if (s < NSITE_) {
                int r = s / PXT_;
                int lpx = s - r * PXT_;
                float xv = xr[it];
                // closed-form uniform cubic B-spline, knots t_j = 0.4j-2.2
                float ua = (xv + 2.2f) * 2.5f;
                float mf = floorf(ua);
                float u = ua - mf;
                bool ok = (ua >= 0.0f) && (ua < 11.0f);
                float u2 = u * u, u3 = u2 * u;
                const float c6 = 1.0f / 6.0f;
                float Bm  = u3 * c6;
                float Bm1 = (-3.f * u3 + 3.f * u2 + 3.f * u + 1.f) * c6;
                float Bm2 = (3.f * u3 - 6.f * u2 + 4.f) * c6;
                float om = 1.f - u;
                float Bm3 = om * om * om * c6;
                // window placement: shorts (m-2..m+1) = [Bm3,Bm2,Bm1,Bm];
                // short 0 overwritten by silu; shorts >=10 dropped (q<5);
                // short 9 is the zero-weight pad.
                unsigned P0 = pack2(Bm3, Bm2);
                unsigned P1 = pack2(Bm1, Bm);
                int sh = ok ? ((int)mf - 2) : 99;
                int a = sh >> 1;
                bool odd = sh & 1;
                unsigned Q0 = odd ? (P0 << 16) : P0;
                unsigned Q1 = odd ? ((P0 >> 16) | (P1 << 16)) : P1;
                unsigned Q2 = odd ? (P1 >> 16) : 0u;
                unsigned wq[5];
#pragma unroll
                for (int q = 0; q < 5; ++q)
                    wq[q] = (q == a) ? Q0 : (q == a + 1) ? Q1 : (q == a + 2) ? Q2 : 0u;
                float sil = xv * __builtin_amdgcn_rcpf(1.f + __expf(-xv));
                wq[0] = (wq[0] & 0xFFFF0000u) | (unsigned)f2bf(sil);
                unsigned* dst = (unsigned*)(lA + r * LROWT_ + lpx * LPIX_ + ci * 20);
#pragma unroll
                for (int q = 0; q < 5; ++q) dst[q] = wq[q];
            }
        }
    }

    int lane = tid & 63, wv = tid >> 6;
    int lrow = lane & 15, khalf = lane >> 4;
    int p = wv & 1;    // row pair within the 4-row group
    int th = wv >> 1;  // tap half: taps th, th+2, th+4, ...

    // B fragments (both nt halves of this wave's taps) double-buffered;
    // first tap's slab prefetched before the barrier.
    short8 B[2][5][2];
#pragma unroll
    for (int c = 0; c < 5; ++c)
#pragma unroll
        for (int nt = 0; nt < 2; ++nt)
            B[0][c][nt] = *(const short8*)(wpk +
                ((size_t)(((th * 2 + nt) * 5 + c)) * 64 + lane) * 8);

    __syncthreads();

    // ---- Phase 2: rows (h0+2p, h0+2p+1) x 16 px x 32 ch over ~half the taps
    f32x4 acc[2][2] = {{{0.f,0.f,0.f,0.f},{0.f,0.f,0.f,0.f}},
                       {{0.f,0.f,0.f,0.f},{0.f,0.f,0.f,0.f}}};

#pragma unroll
    for (int ti = 0; ti < 5; ++ti) {
        int tap = th + 2 * ti;
        if (tap > 8) break;     // th=1 has 4 taps
        int cur = ti & 1, nxt = cur ^ 1;
        int tapn = tap + 2;
        if (tapn <= 8) {
#pragma unroll
            for (int c = 0; c < 5; ++c)
#pragma unroll
                for (int nt = 0; nt < 2; ++nt)
                    B[nxt][c][nt] = *(const short8*)(wpk +
                        ((size_t)(((tapn * 2 + nt) * 5 + c)) * 64 + lane) * 8);
        }
        int ki = tap / 3, kj = tap - ki * 3;
        const char* abase = lA + (2 * p + ki) * LROWT_ + (lrow + kj) * LPIX_ + khalf * 16;
        __builtin_amdgcn_s_setprio(1);
#pragma unroll
        for (int c = 0; c < 5; ++c) {
            short8 a0 = *(const short8*)(abase + c * 64);
            short8 a1 = *(const short8*)(abase + LROWT_ + c * 64);
            acc[0][0] = __builtin_amdgcn_mfma_f32_16x16x32_bf16(a0, B[cur][c][0], acc[0][0], 0, 0, 0);
            acc[0][1] = __builtin_amdgcn_mfma_f32_16x16x32_bf16(a0, B[cur][c][1], acc[0][1], 0, 0, 0);
            acc[1][0] = __builtin_amdgcn_mfma_f32_16x16x32_bf16(a1, B[cur][c][0], acc[1][0], 0, 0, 0);
            acc[1][1] = __builtin_amdgcn_mfma_f32_16x16x32_bf16(a1, B[cur][c][1], acc[1][1], 0, 0, 0);
        }
        __builtin_amdgcn_s_setprio(0);
    }

    // ---- Cross-wave tap reduction via LDS scratch (overlaid on dead lA).
    // Stride 17 floats (68 B) -> banks (17*lane+4q)%32 cover all 32, 2-way free.
    __syncthreads();   // all MFMAs done; lA reusable
    float* scr = (float*)lA;
    int sbase = (p * 64 + lane) * 17;
    if (th == 1) {     // th=1 (4 taps) finishes first; it publishes
#pragma unroll
        for (int mi = 0; mi < 2; ++mi)
#pragma unroll
            for (int nt = 0; nt < 2; ++nt)
                *(f32x4*)(scr + sbase + (mi * 2 + nt) * 4) = acc[mi][nt];
    }
    __syncthreads();
    if (th == 0) {
        float* ob = out + (size_t)bb * COUT_ * (H_ * W_) + w0 + khalf * 4;
#pragma unroll
        for (int mi = 0; mi < 2; ++mi) {
            int hh = h0 + 2 * p + mi;
#pragma unroll
            for (int nt = 0; nt < 2; ++nt) {
                f32x4 v = acc[mi][nt];
                v += *(const f32x4*)(scr + sbase + (mi * 2 + nt) * 4);
                int och = nt * 16 + lrow;
                __builtin_nontemporal_store(v,
                    (f32x4*)(ob + (size_t)och * (H_ * W_) + (size_t)hh * W_));
            }
        }
    }
}

// Fallback (only if workspace is too small): direct fp32 compute, slow but correct.
__device__ __forceinline__ void kan_feat_ref(float xv, float* f) {
    float ua = (xv + 2.2f) * 2.5f;
    float mf = floorf(ua);
    int m = (int)mf;
    float u = ua - mf;
    bool ok = (ua >= 0.0f) && (ua < 11.0f);
    float u2 = u * u, u3 = u2 * u;
    const float c6 = 1.0f / 6.0f;
    float Bm  = u3 * c6;
    float Bm1 = (-3.f * u3 + 3.f * u2 + 3.f * u + 1.f) * c6;
    float Bm2 = (3.f * u3 - 6.f * u2 + 4.f) * c6;
    float om = 1.f - u;
    float Bm3 = om * om * om * c6;
    if (!ok) { Bm = 0.f; Bm1 = 0.f; Bm2 = 0.f; Bm3 = 0.f; }
    f[0] = xv / (1.f + __expf(-xv));
#pragma unroll
    for (int j = 0; j < 8; ++j) {
        float v = 0.f;
        v = (m == j)     ? Bm  : v;
        v = (m == j + 1) ? Bm1 : v;
        v = (m == j + 2) ? Bm2 : v;
        v = (m == j + 3) ? Bm3 : v;
        f[1 + j] = v;
    }
}

__global__ void kan_direct(const float* __restrict__ x, const float* __restrict__ bw,
                           const float* __restrict__ sw, const float* __restrict__ sc,
                           float* __restrict__ out) {
    int idx = blockIdx.x * 256 + threadIdx.x;
    if (idx >= NBATCH_ * COUT_ * H_ * W_) return;
    int w = idx & 63, hh = (idx >> 6) & 63, o = (idx >> 12) & 31, b = idx >> 17;
    float acc = 0.0f;
    for (int i = 0; i < CIN_; ++i)
        for (int ki = 0; ki < 3; ++ki)
            for (int kj = 0; kj < 3; ++kj) {
                int hy = hh + ki - 1, wx = w + kj - 1;
                float xv = (hy >= 0 && hy < H_ && wx >= 0 && wx < W_)
                               ? x[(((size_t)b * CIN_ + i) * H_ + hy) * W_ + wx]
                               : 0.0f;
                float f[9];
                kan_feat_ref(xv, f);
                int idx9 = (o * CIN_ + i) * 9 + ki * 3 + kj;
                float a = f[0] * bw[idx9];
                float s = sc[idx9];
#pragma unroll
                for (int cc = 0; cc < 8; ++cc) a += f[1 + cc] * sw[idx9 * 8 + cc] * s;
                acc += a;
            }
    out[idx] = acc;
}

extern "C" void kernel_launch(void* const* d_in, const int* in_sizes, int n_in,
                              void* d_out, int out_size, void* d_ws, size_t ws_size,
                              hipStream_t stream) {
    const float* x  = (const float*)d_in[0];
    const float* bw = (const float*)d_in[1];
    const float* sw = (const float*)d_in[2];
    const float* sc = (const float*)d_in[3];
    float* out = (float*)d_out;

    size_t need = (size_t)9 * 2 * 5 * 64 * 8 * 2;   // 92,160 B packed weights
    if (ws_size >= need) {
        unsigned short* wpk = (unsigned short*)d_ws;
        kan_packw<<<dim3(18), 256, 0, stream>>>(bw, sw, sc, wpk);
        kan_fused<<<dim3(NBATCH_ * 64), 256, 0, stream>>>(x, wpk, out);
    } else {
        kan_direct<<<dim3((NBATCH_ * COUT_ * H_ * W_ + 255) / 256), 256, 0, stream>>>(
            x, bw, sw, sc, out);
    }
}